// Round 1
// baseline (202.056 us; speedup 1.0000x reference)
//
#include <hip/hip_runtime.h>
#include <math.h>

// ExplaiNN fused forward: B=128, N=300, L=600, K=19, C1=100, PS=7
// LC=582, LP=83, NC=2
#define EPS_ 1e-5f

// ---------------------------------------------------------------------------
// Kernel A: conv1d(4ch,K=19) + bias + bn1 + exp + maxpool(7,7)
// grid (100, 128): blockIdx.x = n-tile (3 units), blockIdx.y = b. 256 threads.
// Threads [0,249): nl = t/83 in [0,3), p = t%83 pooled index.
// Output layout pooled[n][b][p]  (n*128*83 + b*83 + p) for kB's b-tiling.
// ---------------------------------------------------------------------------
__global__ __launch_bounds__(256) void kA(
        const float* __restrict__ x,        // [128,4,600]
        const float* __restrict__ conv_w,   // [300,4,19]
        const float* __restrict__ conv_b,   // [300]
        const float* __restrict__ g1, const float* __restrict__ b1,
        const float* __restrict__ m1, const float* __restrict__ v1,
        float* __restrict__ pooled)         // [300,128,83]
{
    __shared__ float xs[4 * 600];
    __shared__ float sw[3 * 76];
    __shared__ float sA[3], sB[3];
    const int tid = threadIdx.x;
    const int b   = blockIdx.y;
    const int n0  = blockIdx.x * 3;

    for (int i = tid; i < 4 * 600; i += 256) xs[i] = x[b * 2400 + i];
    for (int i = tid; i < 3 * 76;  i += 256) sw[i] = conv_w[n0 * 76 + i];
    if (tid < 3) {
        const int n = n0 + tid;
        const float A = g1[n] * rsqrtf(v1[n] + EPS_);
        sA[tid] = A;
        // bn input is conv + conv_b:  A*(conv+cb-m)+b = A*conv + (A*(cb-m)+b)
        sB[tid] = A * (conv_b[n] - m1[n]) + b1[n];
    }
    __syncthreads();

    if (tid < 249) {
        const int nl = tid / 83;
        const int p  = tid % 83;
        const int base = 7 * p;            // window covers conv pos [7p, 7p+6]
        float acc[7];
        #pragma unroll
        for (int q = 0; q < 7; ++q) acc[q] = 0.f;

        #pragma unroll
        for (int c = 0; c < 4; ++c) {
            float xv[25];                  // x window: 7 outputs + K-1 overlap
            #pragma unroll
            for (int d = 0; d < 25; ++d) xv[d] = xs[c * 600 + base + d];
            #pragma unroll
            for (int k = 0; k < 19; ++k) {
                const float wv = sw[nl * 76 + c * 19 + k];
                #pragma unroll
                for (int q = 0; q < 7; ++q)
                    acc[q] = fmaf(xv[q + k], wv, acc[q]);
            }
        }
        const float A = sA[nl], Bc = sB[nl];
        // exp is monotone increasing -> max then exp (works for any sign of A)
        float mx = -INFINITY;
        #pragma unroll
        for (int q = 0; q < 7; ++q) mx = fmaxf(mx, fmaf(A, acc[q], Bc));
        const int n = n0 + nl;
        pooled[(size_t)n * (128 * 83) + b * 83 + p] = __expf(mx);
    }
}

// ---------------------------------------------------------------------------
// Kernel B: fc1 (dot-83 per h) + bn2 + relu + fc2 (dot-100) + bn3 + relu
// grid (8, 300): blockIdx.x = b-tile (16 b), blockIdx.y = n. 256 threads.
// Stage fc1_w[n] (100x83 = 33 KB) once per block -> 16x reuse across b.
// ---------------------------------------------------------------------------
__global__ __launch_bounds__(256) void kB(
        const float* __restrict__ pooled,   // [300,128,83]
        const float* __restrict__ fc1_w,    // [300,100,83]
        const float* __restrict__ fc1_b,    // [300,100]
        const float* __restrict__ g2, const float* __restrict__ b2,
        const float* __restrict__ m2, const float* __restrict__ v2,
        const float* __restrict__ fc2_w,    // [300,100]
        const float* __restrict__ fc2_b,    // [300]
        const float* __restrict__ g3, const float* __restrict__ b3,
        const float* __restrict__ m3, const float* __restrict__ v3,
        float* __restrict__ sout)           // [128,300]
{
    __shared__ float sW[100 * 83];
    __shared__ float sP[16 * 83];
    __shared__ float sAct[16 * 100];
    __shared__ float sw2[100];
    __shared__ float sA2[100], sC2[100];
    const int tid = threadIdx.x;
    const int n   = blockIdx.y;
    const int b0  = blockIdx.x * 16;

    for (int i = tid; i < 100 * 83; i += 256) sW[i] = fc1_w[(size_t)n * 8300 + i];
    for (int i = tid; i < 16 * 83;  i += 256)
        sP[i] = pooled[(size_t)n * (128 * 83) + b0 * 83 + i];
    if (tid < 100) {
        const int i = n * 100 + tid;
        const float A = g2[i] * rsqrtf(v2[i] + EPS_);
        sA2[tid] = A;
        // bn2 input is dot + fc1_b: fold bias into offset
        sC2[tid] = A * (fc1_b[i] - m2[i]) + b2[i];
        sw2[tid] = fc2_w[i];
    }
    __syncthreads();

    const int bl = tid & 15;      // b within tile
    const int hi = tid >> 4;      // h sub-index
    for (int hb = 0; hb < 7; ++hb) {
        const int h = hb * 16 + hi;
        if (h < 100) {
            float dot = 0.f;
            for (int p = 0; p < 83; ++p)
                dot = fmaf(sW[h * 83 + p], sP[bl * 83 + p], dot);
            const float z = fmaf(sA2[h], dot, sC2[h]);
            sAct[bl * 100 + h] = fmaxf(z, 0.f);
        }
    }
    __syncthreads();

    // fc2: 16 groups of 16 lanes; group g = b index, lane j sums h = j,j+16,...
    const int g = tid >> 4, j = tid & 15;
    float acc = 0.f;
    for (int h = j; h < 100; h += 16) acc += sAct[g * 100 + h] * sw2[h];
    #pragma unroll
    for (int off = 8; off > 0; off >>= 1) acc += __shfl_xor(acc, off, 16);
    if (j == 0) {
        const float val = acc + fc2_b[n];
        const float A3 = g3[n] * rsqrtf(v3[n] + EPS_);
        const float z = A3 * (val - m3[n]) + b3[n];
        sout[(size_t)(b0 + g) * 300 + n] = fmaxf(z, 0.f);
    }
}

// ---------------------------------------------------------------------------
// Kernel C: out[b,c] = sum_n sout[b,n] * final_w[c,n] + final_b[c]
// grid 128 blocks x 64 threads (one wave per b).
// ---------------------------------------------------------------------------
__global__ __launch_bounds__(64) void kC(
        const float* __restrict__ sout,     // [128,300]
        const float* __restrict__ fw,       // [2,300]
        const float* __restrict__ fb,       // [2]
        float* __restrict__ out)            // [128,2]
{
    const int b = blockIdx.x, t = threadIdx.x;
    float a0 = 0.f, a1 = 0.f;
    for (int nn = t; nn < 300; nn += 64) {
        const float v = sout[b * 300 + nn];
        a0 = fmaf(v, fw[nn], a0);
        a1 = fmaf(v, fw[300 + nn], a1);
    }
    #pragma unroll
    for (int off = 32; off > 0; off >>= 1) {
        a0 += __shfl_xor(a0, off, 64);
        a1 += __shfl_xor(a1, off, 64);
    }
    if (t == 0) {
        out[b * 2 + 0] = a0 + fb[0];
        out[b * 2 + 1] = a1 + fb[1];
    }
}

extern "C" void kernel_launch(void* const* d_in, const int* in_sizes, int n_in,
                              void* d_out, int out_size, void* d_ws, size_t ws_size,
                              hipStream_t stream) {
    const float* x      = (const float*)d_in[0];
    const float* conv_w = (const float*)d_in[1];
    const float* conv_b = (const float*)d_in[2];
    const float* g1 = (const float*)d_in[3];
    const float* b1 = (const float*)d_in[4];
    const float* m1 = (const float*)d_in[5];
    const float* v1 = (const float*)d_in[6];
    const float* fc1_w = (const float*)d_in[7];
    const float* fc1_b = (const float*)d_in[8];
    const float* g2 = (const float*)d_in[9];
    const float* b2 = (const float*)d_in[10];
    const float* m2 = (const float*)d_in[11];
    const float* v2 = (const float*)d_in[12];
    const float* fc2_w = (const float*)d_in[13];
    const float* fc2_b = (const float*)d_in[14];
    const float* g3 = (const float*)d_in[15];
    const float* b3 = (const float*)d_in[16];
    const float* m3 = (const float*)d_in[17];
    const float* v3 = (const float*)d_in[18];
    const float* fw = (const float*)d_in[19];
    const float* fb = (const float*)d_in[20];
    float* out = (float*)d_out;

    float* pooled = (float*)d_ws;                       // 300*128*83 floats
    float* sout   = pooled + (size_t)300 * 128 * 83;    // 128*300 floats

    kA<<<dim3(100, 128), 256, 0, stream>>>(x, conv_w, conv_b, g1, b1, m1, v1, pooled);
    kB<<<dim3(8, 300), 256, 0, stream>>>(pooled, fc1_w, fc1_b, g2, b2, m2, v2,
                                         fc2_w, fc2_b, g3, b3, m3, v3, sout);
    kC<<<128, 64, 0, stream>>>(sout, fw, fb, out);
}

// Round 2
// 201.603 us; speedup vs baseline: 1.0022x; 1.0022x over previous
//
#include <hip/hip_runtime.h>
#include <math.h>

// ExplaiNN fused forward: B=128, N=300, L=600, K=19, C1=100, PS=7
// LC=582, LP=83, NC=2
#define EPS_ 1e-5f

// ---------------------------------------------------------------------------
// Kernel A: conv1d(4ch,K=19) + bias + bn1 + exp + maxpool(7,7)
// grid (34, 128): blockIdx.x = n-tile (9 units), blockIdx.y = b. 256 threads.
// Thread t<249: nl = t/83 in [0,3), p = t%83. Each thread computes 3 n's
// (n = n0 + nl*3 + m) with a 7-deep sliding register window over x so the
// x-window loads (25/channel) amortize over 3*133=399 FMAs/channel.
// Output layout pooled[n][b][p] for kB's b-tiling.
// ---------------------------------------------------------------------------
__global__ __launch_bounds__(256) void kA(
        const float* __restrict__ x,        // [128,4,600]
        const float* __restrict__ conv_w,   // [300,4,19]
        const float* __restrict__ conv_b,   // [300]
        const float* __restrict__ g1, const float* __restrict__ b1,
        const float* __restrict__ m1, const float* __restrict__ v1,
        float* __restrict__ pooled)         // [300,128,83]
{
    __shared__ __align__(16) float xs[4 * 600];
    __shared__ float sw[9 * 76];
    __shared__ float sA[9], sB[9];
    const int tid = threadIdx.x;
    const int b   = blockIdx.y;
    const int n0  = blockIdx.x * 9;

    // stage x[b] (9.6 KB) via float4
    {
        const float4* src = reinterpret_cast<const float4*>(x + (size_t)b * 2400);
        float4* dst = reinterpret_cast<float4*>(xs);
        for (int i = tid; i < 600; i += 256) dst[i] = src[i];
    }
    for (int i = tid; i < 9 * 76; i += 256) {
        const int gi = n0 * 76 + i;
        sw[i] = (gi < 300 * 76) ? conv_w[gi] : 0.f;
    }
    if (tid < 9) {
        const int n = n0 + tid;
        if (n < 300) {
            const float A = g1[n] * rsqrtf(v1[n] + EPS_);
            sA[tid] = A;
            sB[tid] = A * (conv_b[n] - m1[n]) + b1[n];  // fold conv bias into bn
        } else { sA[tid] = 0.f; sB[tid] = 0.f; }
    }
    __syncthreads();

    if (tid < 249) {
        const int nl = tid / 83;       // 0..2
        const int p  = tid % 83;
        const int base = 7 * p;        // conv positions [7p, 7p+6]
        float acc[3][7];
        #pragma unroll
        for (int m = 0; m < 3; ++m)
            #pragma unroll
            for (int q = 0; q < 7; ++q) acc[m][q] = 0.f;

        for (int c = 0; c < 4; ++c) {
            const float* xc = &xs[c * 600 + base];
            const float* wc = &sw[nl * 3 * 76 + c * 19];
            float win[7];
            #pragma unroll
            for (int j = 0; j < 7; ++j) win[j] = xc[j];
            #pragma unroll
            for (int k = 0; k < 19; ++k) {
                const float w0 = wc[k];
                const float w1 = wc[76 + k];
                const float w2 = wc[152 + k];
                #pragma unroll
                for (int q = 0; q < 7; ++q) {
                    acc[0][q] = fmaf(win[q], w0, acc[0][q]);
                    acc[1][q] = fmaf(win[q], w1, acc[1][q]);
                    acc[2][q] = fmaf(win[q], w2, acc[2][q]);
                }
                if (k < 18) {
                    #pragma unroll
                    for (int j = 0; j < 6; ++j) win[j] = win[j + 1];
                    win[6] = xc[k + 7];
                }
            }
        }
        #pragma unroll
        for (int m = 0; m < 3; ++m) {
            const int n = n0 + nl * 3 + m;
            if (n < 300) {
                const float A = sA[nl * 3 + m], Bc = sB[nl * 3 + m];
                float mx = -INFINITY;  // exp monotone -> max before exp
                #pragma unroll
                for (int q = 0; q < 7; ++q) mx = fmaxf(mx, fmaf(A, acc[m][q], Bc));
                pooled[(size_t)n * (128 * 83) + b * 83 + p] = __expf(mx);
            }
        }
    }
}

// ---------------------------------------------------------------------------
// Kernel B: fc1 (K=83) + bn2 + relu + fc2 (dot-100) + bn3 + relu
// grid (2, 300): blockIdx.x = b-tile (64 b), blockIdx.y = n. 256 threads.
// Register-tiled GEMM: thread (bg=t>>4, hg=t&15) computes a 4b x 7h tile from
// k-padded (83->84, zero col) LDS buffers via float4 reads. W reads broadcast
// across the 4 bg lanes sharing hg; P reads broadcast across the 16 hg lanes.
// fc2 fused: per-thread partials -> 16x64 LDS tree reduce -> bn3+relu.
// ---------------------------------------------------------------------------
__global__ __launch_bounds__(256) void kB(
        const float* __restrict__ pooled,   // [300,128,83]
        const float* __restrict__ fc1_w,    // [300,100,83]
        const float* __restrict__ fc1_b,    // [300,100]
        const float* __restrict__ g2, const float* __restrict__ b2,
        const float* __restrict__ m2, const float* __restrict__ v2,
        const float* __restrict__ fc2_w,    // [300,100]
        const float* __restrict__ fc2_b,    // [300]
        const float* __restrict__ g3, const float* __restrict__ b3,
        const float* __restrict__ m3, const float* __restrict__ v3,
        float* __restrict__ sout)           // [128,300]
{
    __shared__ __align__(16) float sW[112 * 84];   // h rows 100..111 zero
    __shared__ __align__(16) float sP[64 * 84];    // k col 83 zero
    __shared__ float sRed[16][64];
    __shared__ float sA2[112], sC2[112], sw2[112];
    const int tid = threadIdx.x;
    const int n   = blockIdx.y;
    const int b0  = blockIdx.x * 64;

    for (int i = tid; i < 112 * 84; i += 256) {
        const int h = i / 84, k = i - h * 84;
        sW[i] = (h < 100 && k < 83) ? fc1_w[(size_t)n * 8300 + h * 83 + k] : 0.f;
    }
    for (int i = tid; i < 64 * 84; i += 256) {
        const int bl = i / 84, p = i - bl * 84;
        sP[i] = (p < 83) ? pooled[(size_t)n * (128 * 83) + (b0 + bl) * 83 + p] : 0.f;
    }
    if (tid < 112) {
        if (tid < 100) {
            const int i = n * 100 + tid;
            const float A = g2[i] * rsqrtf(v2[i] + EPS_);
            sA2[tid] = A;
            sC2[tid] = A * (fc1_b[i] - m2[i]) + b2[i];  // fold fc1 bias into bn2
            sw2[tid] = fc2_w[i];
        } else { sA2[tid] = 0.f; sC2[tid] = 0.f; sw2[tid] = 0.f; }
    }
    __syncthreads();

    const int bg = tid >> 4;       // 0..15 -> b rows bg*4..bg*4+3
    const int hg = tid & 15;       // 0..15 -> h cols hg*7..hg*7+6
    float acc[4][7];
    #pragma unroll
    for (int i = 0; i < 4; ++i)
        #pragma unroll
        for (int j = 0; j < 7; ++j) acc[i][j] = 0.f;

    for (int k0 = 0; k0 < 84; k0 += 4) {
        float4 wv[7], pv[4];
        #pragma unroll
        for (int j = 0; j < 7; ++j)
            wv[j] = *reinterpret_cast<const float4*>(&sW[(hg * 7 + j) * 84 + k0]);
        #pragma unroll
        for (int i = 0; i < 4; ++i)
            pv[i] = *reinterpret_cast<const float4*>(&sP[(bg * 4 + i) * 84 + k0]);
        #pragma unroll
        for (int i = 0; i < 4; ++i)
            #pragma unroll
            for (int j = 0; j < 7; ++j) {
                acc[i][j] = fmaf(pv[i].x, wv[j].x, acc[i][j]);
                acc[i][j] = fmaf(pv[i].y, wv[j].y, acc[i][j]);
                acc[i][j] = fmaf(pv[i].z, wv[j].z, acc[i][j]);
                acc[i][j] = fmaf(pv[i].w, wv[j].w, acc[i][j]);
            }
    }

    // bn2 + relu + fc2 partials (h>=100 lanes contribute 0 via zeroed params)
    float part[4] = {0.f, 0.f, 0.f, 0.f};
    #pragma unroll
    for (int j = 0; j < 7; ++j) {
        const int h = hg * 7 + j;
        const float a2 = sA2[h], c2 = sC2[h], w2 = sw2[h];
        #pragma unroll
        for (int i = 0; i < 4; ++i) {
            const float z = fmaxf(fmaf(a2, acc[i][j], c2), 0.f);
            part[i] = fmaf(z, w2, part[i]);
        }
    }
    #pragma unroll
    for (int i = 0; i < 4; ++i) sRed[hg][bg * 4 + i] = part[i];
    __syncthreads();

    if (tid < 64) {
        float s = 0.f;
        #pragma unroll
        for (int g = 0; g < 16; ++g) s += sRed[g][tid];
        s += fc2_b[n];
        const float A3 = g3[n] * rsqrtf(v3[n] + EPS_);
        const float z = A3 * (s - m3[n]) + b3[n];
        sout[(size_t)(b0 + tid) * 300 + n] = fmaxf(z, 0.f);
    }
}

// ---------------------------------------------------------------------------
// Kernel C: out[b,c] = sum_n sout[b,n] * final_w[c,n] + final_b[c]
// ---------------------------------------------------------------------------
__global__ __launch_bounds__(64) void kC(
        const float* __restrict__ sout,     // [128,300]
        const float* __restrict__ fw,       // [2,300]
        const float* __restrict__ fb,
        float* __restrict__ out)            // [128,2]
{
    const int b = blockIdx.x, t = threadIdx.x;
    float a0 = 0.f, a1 = 0.f;
    for (int nn = t; nn < 300; nn += 64) {
        const float v = sout[b * 300 + nn];
        a0 = fmaf(v, fw[nn], a0);
        a1 = fmaf(v, fw[300 + nn], a1);
    }
    #pragma unroll
    for (int off = 32; off > 0; off >>= 1) {
        a0 += __shfl_xor(a0, off, 64);
        a1 += __shfl_xor(a1, off, 64);
    }
    if (t == 0) {
        out[b * 2 + 0] = a0 + fb[0];
        out[b * 2 + 1] = a1 + fb[1];
    }
}

extern "C" void kernel_launch(void* const* d_in, const int* in_sizes, int n_in,
                              void* d_out, int out_size, void* d_ws, size_t ws_size,
                              hipStream_t stream) {
    const float* x      = (const float*)d_in[0];
    const float* conv_w = (const float*)d_in[1];
    const float* conv_b = (const float*)d_in[2];
    const float* g1 = (const float*)d_in[3];
    const float* b1 = (const float*)d_in[4];
    const float* m1 = (const float*)d_in[5];
    const float* v1 = (const float*)d_in[6];
    const float* fc1_w = (const float*)d_in[7];
    const float* fc1_b = (const float*)d_in[8];
    const float* g2 = (const float*)d_in[9];
    const float* b2 = (const float*)d_in[10];
    const float* m2 = (const float*)d_in[11];
    const float* v2 = (const float*)d_in[12];
    const float* fc2_w = (const float*)d_in[13];
    const float* fc2_b = (const float*)d_in[14];
    const float* g3 = (const float*)d_in[15];
    const float* b3 = (const float*)d_in[16];
    const float* m3 = (const float*)d_in[17];
    const float* v3 = (const float*)d_in[18];
    const float* fw = (const float*)d_in[19];
    const float* fb = (const float*)d_in[20];
    float* out = (float*)d_out;

    float* pooled = (float*)d_ws;                       // 300*128*83 floats
    float* sout   = pooled + (size_t)300 * 128 * 83;    // 128*300 floats

    kA<<<dim3(34, 128), 256, 0, stream>>>(x, conv_w, conv_b, g1, b1, m1, v1, pooled);
    kB<<<dim3(2, 300), 256, 0, stream>>>(pooled, fc1_w, fc1_b, g2, b2, m2, v2,
                                         fc2_w, fc2_b, g3, b3, m3, v3, sout);
    kC<<<128, 64, 0, stream>>>(sout, fw, fb, out);
}